// Round 5
// baseline (283.371 us; speedup 1.0000x reference)
//
#include <hip/hip_runtime.h>
#include <math.h>

typedef unsigned short u16;
typedef unsigned int   u32;
typedef unsigned long long u64;

#define T_PRED 30
#define BN 2048
#define DD 256
#define DHH 128
#define ESHIFT 64.0f

typedef __attribute__((ext_vector_type(8))) short short8;   // 8 x bf16
typedef __attribute__((ext_vector_type(4))) float f32x4;

// ---- workspace layout (~38.3 MB) ----
// 0: f32 nce_acc | 8: u32 done
#define WS_S      4096                     // f32 S[29][2048] partial exp-sums
#define WS_TABLE  (WS_S + 237568)          // u64 table[2048]
#define WS_LSE    (WS_TABLE + 16384)       // f32 lse29[2048]
#define WS_WH     (WS_LSE + 8192)          // u16 W^T hi [30][128][256]
#define WS_WL     (WS_WH + 1966080)
#define WS_RH     (WS_WL + 1966080)        // u16 rep hi [2048][128]
#define WS_RL     (WS_RH + 524288)
#define WS_GH     (WS_RL + 524288)         // u16 G hi [30][2048][128]
#define WS_GL29   (WS_GH + 15728640)       // u16 G lo (t=29) [2048][128]
#define WS_T29    (WS_GL29 + 524288)       // f32 tot29 [2048][2048]

__device__ __forceinline__ u16 bf16_rne(float f) {
    u32 u = __float_as_uint(f);
    u32 r = u + 0x7fffu + ((u >> 16) & 1u);
    return (u16)(r >> 16);
}

__device__ __forceinline__ short8 pack_hi8(const float* f) {   // truncation split
    short8 r;
#pragma unroll
    for (int k = 0; k < 8; ++k) r[k] = (short)(u16)(__float_as_uint(f[k]) >> 16);
    return r;
}
__device__ __forceinline__ short8 pack_lo8(const float* f) {
    short8 r;
#pragma unroll
    for (int k = 0; k < 8; ++k) {
        float hf = __uint_as_float(__float_as_uint(f[k]) & 0xffff0000u);
        r[k] = (short)bf16_rne(f[k] - hf);
    }
    return r;
}

// ---------------- prep: W transpose+split, rep split ----------------------
__global__ __launch_bounds__(256) void prep_kernel(
    const float* __restrict__ rep, const float* __restrict__ Ww,
    u16* __restrict__ Rh, u16* __restrict__ Rl,
    u16* __restrict__ Wh, u16* __restrict__ Wl)
{
    const int bx = blockIdx.x, tid = threadIdx.x;
    if (bx < 120) {
        __shared__ float tile[64][132];
        const int t = bx >> 2, d0 = (bx & 3) * 64;
        for (int it = 0; it < 8; ++it) {
            int idx = tid + it * 256;
            int row = idx >> 5, off = (idx & 31) * 4;
            *(float4*)&tile[row][off] =
                *(const float4*)&Ww[((size_t)t * DD + d0 + row) * DHH + off];
        }
        __syncthreads();
        const int h = tid & 127, part = tid >> 7;
        for (int dd = 0; dd < 32; ++dd) {
            int d = part * 32 + dd;
            float v = tile[d][h];
            u16 hb = bf16_rne(v);
            float hf = __uint_as_float((u32)hb << 16);
            size_t o = (size_t)t * DHH * DD + (size_t)h * DD + d0 + d;
            Wh[o] = hb;
            Wl[o] = bf16_rne(v - hf);
        }
    } else {
        int base = (bx - 120) * 256 + tid;            // float4 index, 8 blocks
        for (int p = 0; p < 32; ++p) {
            int i = base + p * 2048;
            float4 v = ((const float4*)rep)[i];
            float vv[4] = {v.x, v.y, v.z, v.w};
            u16 h[4], l[4];
#pragma unroll
            for (int k = 0; k < 4; ++k) {
                h[k] = bf16_rne(vv[k]);
                float hf = __uint_as_float((u32)h[k] << 16);
                l[k] = bf16_rne(vv[k] - hf);
            }
            ((ushort4*)Rh)[i] = make_ushort4(h[0], h[1], h[2], h[3]);
            ((ushort4*)Rl)[i] = make_ushort4(l[0], l[1], l[2], l[3]);
        }
    }
}

// ---------------- G[t] = E[t] @ W[t]^T : LDS-free, 64-row tiles ------------
// grid (32, 30). 1-pass for t<29, 3-pass split for t=29.
__global__ __launch_bounds__(256) void g_kernel(
    const float* __restrict__ E, const u16* __restrict__ Wh,
    const u16* __restrict__ Wl, u16* __restrict__ Gh, u16* __restrict__ Gl29)
{
    const int t    = blockIdx.y;
    const int row0 = blockIdx.x * 64;
    const int tid  = threadIdx.x;
    const int lane = tid & 63;
    const int w    = tid >> 6;
    const int ml   = lane & 15;
    const int quad = lane >> 4;
    const int wr   = (w & 1) * 32;
    const int wc   = (w >> 1) * 64;
    const bool p3  = (t == T_PRED - 1);

    f32x4 acc[2][4];
#pragma unroll
    for (int i = 0; i < 2; ++i)
#pragma unroll
        for (int j = 0; j < 4; ++j) acc[i][j] = (f32x4){0.f, 0.f, 0.f, 0.f};

#pragma unroll 2
    for (int kc = 0; kc < 8; ++kc) {
        short8 ah[2], al[2], bh[4], bl[4];
#pragma unroll
        for (int i = 0; i < 2; ++i) {
            const float* ep = E + ((size_t)t * BN + row0 + wr + i * 16 + ml) * DD
                                + kc * 32 + quad * 8;
            float4 e0 = *(const float4*)ep;
            float4 e1 = *(const float4*)(ep + 4);
            float f[8] = {e0.x, e0.y, e0.z, e0.w, e1.x, e1.y, e1.z, e1.w};
            ah[i] = pack_hi8(f);
            if (p3) al[i] = pack_lo8(f);
        }
#pragma unroll
        for (int j = 0; j < 4; ++j) {
            size_t o = (size_t)t * DHH * DD + (size_t)(wc + j * 16 + ml) * DD
                     + kc * 32 + quad * 8;
            bh[j] = *(const short8*)(Wh + o);
            if (p3) bl[j] = *(const short8*)(Wl + o);
        }
#pragma unroll
        for (int i = 0; i < 2; ++i)
#pragma unroll
            for (int j = 0; j < 4; ++j) {
                acc[i][j] = __builtin_amdgcn_mfma_f32_16x16x32_bf16(ah[i], bh[j], acc[i][j], 0, 0, 0);
                if (p3) {
                    acc[i][j] = __builtin_amdgcn_mfma_f32_16x16x32_bf16(ah[i], bl[j], acc[i][j], 0, 0, 0);
                    acc[i][j] = __builtin_amdgcn_mfma_f32_16x16x32_bf16(al[i], bh[j], acc[i][j], 0, 0, 0);
                }
            }
    }

#pragma unroll
    for (int i = 0; i < 2; ++i)
#pragma unroll
        for (int j = 0; j < 4; ++j)
#pragma unroll
            for (int r = 0; r < 4; ++r) {
                int row = row0 + wr + i * 16 + quad * 4 + r;
                int col = wc + j * 16 + ml;
                float v = acc[i][j][r];
                u16 hb = bf16_rne(v);
                Gh[((size_t)t * BN + row) * DHH + col] = hb;
                if (p3) {
                    float hf = __uint_as_float((u32)hb << 16);
                    Gl29[(size_t)row * DHH + col] = bf16_rne(v - hf);
                }
            }
}

// ---------------- nce for t=0..28: fixed-shift exp sums --------------------
// grid (16 rowblk, 4 colchunk, 29 t). Block: 128 rows x 512 cols.
// Partial sums of exp(x - ESHIFT) are cross-block addable -> atomicAdd to S.
__global__ __launch_bounds__(256) void nceA_kernel(
    const u16* __restrict__ Gh, const u16* __restrict__ Rh,
    float* __restrict__ S, float* __restrict__ nce_acc)
{
    const int row0   = blockIdx.x * 128;
    const int cchunk = blockIdx.y * 512;
    const int t      = blockIdx.z;
    const int tid  = threadIdx.x;
    const int lane = tid & 63;
    const int w    = tid >> 6;
    const int ml   = lane & 15;
    const int quad = lane >> 4;
    const int wr   = (w >> 1) * 64;
    const int wc   = (w & 1) * 64;
    const bool dblk = ((row0 >> 9) == (int)blockIdx.y);

    short8 ah[4][4];
#pragma unroll
    for (int i = 0; i < 4; ++i)
#pragma unroll
        for (int kc = 0; kc < 4; ++kc)
            ah[i][kc] = *(const short8*)(Gh +
                ((size_t)t * BN + row0 + wr + i * 16 + ml) * DHH + kc * 32 + quad * 8);

    float ssum[4][4];
#pragma unroll
    for (int i = 0; i < 4; ++i)
#pragma unroll
        for (int r = 0; r < 4; ++r) ssum[i][r] = 0.f;
    float dsum = 0.f;

#pragma unroll 1
    for (int c0 = cchunk; c0 < cchunk + 512; c0 += 128) {
        f32x4 acc[4][4];
#pragma unroll
        for (int i = 0; i < 4; ++i)
#pragma unroll
            for (int j = 0; j < 4; ++j) acc[i][j] = (f32x4){0.f, 0.f, 0.f, 0.f};

#pragma unroll
        for (int kc = 0; kc < 4; ++kc) {
            short8 bh[4];
#pragma unroll
            for (int j = 0; j < 4; ++j)
                bh[j] = *(const short8*)(Rh +
                    (size_t)(c0 + wc + j * 16 + ml) * DHH + kc * 32 + quad * 8);
#pragma unroll
            for (int i = 0; i < 4; ++i)
#pragma unroll
                for (int j = 0; j < 4; ++j)
                    acc[i][j] = __builtin_amdgcn_mfma_f32_16x16x32_bf16(ah[i][kc], bh[j], acc[i][j], 0, 0, 0);
        }

        if (dblk && c0 == row0) {   // the only col-tile containing the diagonal
#pragma unroll
            for (int i = 0; i < 4; ++i)
#pragma unroll
                for (int j = 0; j < 4; ++j)
#pragma unroll
                    for (int r = 0; r < 4; ++r)
                        if (wc + j * 16 + ml == wr + i * 16 + quad * 4 + r)
                            dsum += acc[i][j][r];
        }

#pragma unroll
        for (int i = 0; i < 4; ++i)
#pragma unroll
            for (int r = 0; r < 4; ++r)
                ssum[i][r] += __expf(acc[i][0][r] - ESHIFT)
                            + __expf(acc[i][1][r] - ESHIFT)
                            + __expf(acc[i][2][r] - ESHIFT)
                            + __expf(acc[i][3][r] - ESHIFT);
    }

    // reduce over the 16 ml-lanes sharing each row, then one atomic per row
#pragma unroll
    for (int i = 0; i < 4; ++i)
#pragma unroll
        for (int r = 0; r < 4; ++r) {
            float v = ssum[i][r];
#pragma unroll
            for (int o = 1; o < 16; o <<= 1) v += __shfl_xor(v, o, 64);
            if (ml == 0)
                atomicAdd(S + (size_t)t * BN + row0 + wr + i * 16 + quad * 4 + r, v);
        }
    if (dblk) {
        float dv = dsum;
#pragma unroll
        for (int o = 1; o < 64; o <<= 1) dv += __shfl_xor(dv, o, 64);
        if (lane == 0) atomicAdd(nce_acc, -dv);   // nce_acc holds sum(lse - diag)
    }
}

// ---------------- reduce: nce_acc += sum over (t<29, row) of (64 + log S) --
__global__ __launch_bounds__(256) void nce_reduce_kernel(
    const float* __restrict__ S, float* __restrict__ nce_acc)
{
    __shared__ float part[4];
    const int idx = blockIdx.x * 256 + threadIdx.x;   // 232*256 = 59392 exactly
    float v = ESHIFT + __logf(S[idx]);
#pragma unroll
    for (int o = 1; o < 64; o <<= 1) v += __shfl_xor(v, o, 64);
    if ((threadIdx.x & 63) == 0) part[threadIdx.x >> 6] = v;
    __syncthreads();
    if (threadIdx.x == 0)
        atomicAdd(nce_acc, part[0] + part[1] + part[2] + part[3]);
}

// ---------------- tot29 = G[29] @ rep^T, full 3-pass split, LDS-free -------
__global__ __launch_bounds__(256) void tot29_kernel(
    const u16* __restrict__ Gh, const u16* __restrict__ Gl29,
    const u16* __restrict__ Rh, const u16* __restrict__ Rl,
    float* __restrict__ tot29)
{
    const int row0 = blockIdx.x * 128;
    const int col0 = blockIdx.y * 128;
    const int tid  = threadIdx.x;
    const int lane = tid & 63;
    const int w    = tid >> 6;
    const int ml   = lane & 15;
    const int quad = lane >> 4;
    const int wr   = (w >> 1) * 64;
    const int wc   = (w & 1) * 64;
    const u16* Gh29 = Gh + (size_t)(T_PRED - 1) * BN * DHH;

    f32x4 acc[4][4];
#pragma unroll
    for (int i = 0; i < 4; ++i)
#pragma unroll
        for (int j = 0; j < 4; ++j) acc[i][j] = (f32x4){0.f, 0.f, 0.f, 0.f};

#pragma unroll 1
    for (int kc = 0; kc < 4; ++kc) {
        short8 ah[4], al[4], bh[4], bl[4];
#pragma unroll
        for (int i = 0; i < 4; ++i) {
            size_t o = (size_t)(row0 + wr + i * 16 + ml) * DHH + kc * 32 + quad * 8;
            ah[i] = *(const short8*)(Gh29 + o);
            al[i] = *(const short8*)(Gl29 + o);
        }
#pragma unroll
        for (int j = 0; j < 4; ++j) {
            size_t o = (size_t)(col0 + wc + j * 16 + ml) * DHH + kc * 32 + quad * 8;
            bh[j] = *(const short8*)(Rh + o);
            bl[j] = *(const short8*)(Rl + o);
        }
#pragma unroll
        for (int i = 0; i < 4; ++i)
#pragma unroll
            for (int j = 0; j < 4; ++j) {
                acc[i][j] = __builtin_amdgcn_mfma_f32_16x16x32_bf16(ah[i], bh[j], acc[i][j], 0, 0, 0);
                acc[i][j] = __builtin_amdgcn_mfma_f32_16x16x32_bf16(ah[i], bl[j], acc[i][j], 0, 0, 0);
                acc[i][j] = __builtin_amdgcn_mfma_f32_16x16x32_bf16(al[i], bh[j], acc[i][j], 0, 0, 0);
            }
    }

#pragma unroll
    for (int i = 0; i < 4; ++i)
#pragma unroll
        for (int j = 0; j < 4; ++j)
#pragma unroll
            for (int r = 0; r < 4; ++r)
                tot29[(size_t)(row0 + wr + i * 16 + quad * 4 + r) * BN
                      + col0 + wc + j * 16 + ml] = acc[i][j][r];
}

// ---------------- lse29 per row + t=29 nce contribution --------------------
__global__ __launch_bounds__(256) void lse29_kernel(
    const float* __restrict__ tot29, float* __restrict__ lse29,
    float* __restrict__ nce_acc)
{
    __shared__ float part[4];
    const int lane = threadIdx.x & 63;
    const int wv   = threadIdx.x >> 6;
    const int row  = blockIdx.x * 4 + wv;
    const float* rp = tot29 + (size_t)row * BN;

    float ss = 0.f;
#pragma unroll 1
    for (int p = 0; p < 8; ++p) {
        float4 v = *(const float4*)&rp[p * 256 + lane * 4];
        ss += __expf(v.x - ESHIFT) + __expf(v.y - ESHIFT)
            + __expf(v.z - ESHIFT) + __expf(v.w - ESHIFT);
    }
#pragma unroll
    for (int o = 1; o < 64; o <<= 1) ss += __shfl_xor(ss, o, 64);
    if (lane == 0) {
        float lse = ESHIFT + __logf(ss);
        lse29[row] = lse;
        part[wv] = lse - rp[row];           // lse - diag
    }
    __syncthreads();
    if (threadIdx.x == 0)
        atomicAdd(nce_acc, part[0] + part[1] + part[2] + part[3]);
}

// ---------------- argmax + count + final outputs (last-block pattern) ------
__device__ __forceinline__ u32 fenc(float f) {
    u32 u = __float_as_uint(f);
    return (u & 0x80000000u) ? ~u : (u | 0x80000000u);
}

__global__ __launch_bounds__(256) void argmax_fin_kernel(
    const float* __restrict__ tot29, const float* __restrict__ lse29,
    u64* __restrict__ table, u32* __restrict__ done,
    const float* __restrict__ nce_acc, float* __restrict__ out)
{
    __shared__ u32 lastflag;
    __shared__ int cpart[4];
    const int tid = threadIdx.x;
    const int c   = blockIdx.x * 256 + tid;
    const int b0  = blockIdx.y * 128;

    float best = -3.4e38f; int bi = 0;
    for (int b = b0; b < b0 + 128; ++b) {
        float v = tot29[(size_t)b * BN + c] - lse29[b];
        if (v > best) { best = v; bi = b; }
    }
    u64 key = ((u64)fenc(best) << 32) | (u32)(0xFFFFFFFFu - (u32)bi);
    atomicMax(table + c, key);

    __threadfence();
    if (tid == 0) lastflag = (atomicAdd(done, 1u) == 127u);
    __syncthreads();
    if (!lastflag) return;

    int cnt = 0;
    for (int i = tid; i < BN; i += 256) {
        u64 k = atomicAdd(table + i, 0ull);      // device-coherent read
        u32 b = 0xFFFFFFFFu - (u32)(k & 0xFFFFFFFFull);
        if ((int)b == i) cnt++;
    }
#pragma unroll
    for (int o = 1; o < 64; o <<= 1) cnt += __shfl_xor(cnt, o, 64);
    if ((tid & 63) == 0) cpart[tid >> 6] = cnt;
    __syncthreads();
    if (tid == 0) {
        int correct = cpart[0] + cpart[1] + cpart[2] + cpart[3];
        float nce = atomicAdd((float*)nce_acc, 0.0f);
        out[0] = (float)correct / (float)BN;
        out[1] = nce / (float)(BN * T_PRED);
        out[2] = (float)BN;
        out[3] = (float)(BN * T_PRED);
    }
}

extern "C" void kernel_launch(void* const* d_in, const int* in_sizes, int n_in,
                              void* d_out, int out_size, void* d_ws, size_t ws_size,
                              hipStream_t stream) {
    const float* E   = (const float*)d_in[0];   // [T,B,D]
    const float* rep = (const float*)d_in[1];   // [B,DH]
    const float* Ww  = (const float*)d_in[2];   // [T,D,DH]
    float* out = (float*)d_out;

    char* ws = (char*)d_ws;
    float* nce_acc = (float*)(ws + 0);
    u32*   done    = (u32*)(ws + 8);
    float* S       = (float*)(ws + WS_S);
    u64*   table   = (u64*)(ws + WS_TABLE);
    float* lse29   = (float*)(ws + WS_LSE);
    u16*   Wh      = (u16*)(ws + WS_WH);
    u16*   Wl      = (u16*)(ws + WS_WL);
    u16*   Rh      = (u16*)(ws + WS_RH);
    u16*   Rl      = (u16*)(ws + WS_RL);
    u16*   Gh      = (u16*)(ws + WS_GH);
    u16*   Gl29    = (u16*)(ws + WS_GL29);
    float* tot29   = (float*)(ws + WS_T29);

    hipMemsetAsync(ws, 0, WS_LSE, stream);      // nce_acc, done, S, table
    prep_kernel<<<dim3(128), 256, 0, stream>>>(rep, Ww, Rh, Rl, Wh, Wl);
    g_kernel<<<dim3(32, 30), 256, 0, stream>>>(E, Wh, Wl, Gh, Gl29);
    nceA_kernel<<<dim3(16, 4, 29), 256, 0, stream>>>(Gh, Rh, S, nce_acc);
    nce_reduce_kernel<<<dim3(232), 256, 0, stream>>>(S, nce_acc);
    tot29_kernel<<<dim3(16, 16), 256, 0, stream>>>(Gh, Gl29, Rh, Rl, tot29);
    lse29_kernel<<<dim3(512), 256, 0, stream>>>(tot29, lse29, nce_acc);
    argmax_fin_kernel<<<dim3(8, 16), 256, 0, stream>>>(tot29, lse29, table, done,
                                                       nce_acc, out);
}